// Round 4
// baseline (448.628 us; speedup 1.0000x reference)
//
#include <hip/hip_runtime.h>

#define T_SEQ 512
#define HID 64
#define MB 16             // batch rows per block
#define NTHREADS 1024     // 16 waves: 0-7 layer1 (2 tiles), 8-15 layer2 (2 tiles)
// OPERAND-FLIPPED MFMA: A = weights (regs), B = h (LDS). D[gate-unit][batch].
// LAYER-SPLIT: L1 waves read {h1 x2, x} = 3 b128; L2 waves read {h1 x2, h2 x2} = 4.
// UNIT PERMUTATION: LDS position p holds unit U(p) = (p&~7)+((p&7)>>1)+((p&1)<<2)
// -> thread (wl,quad) owns units at adjacent positions: single packed b32 h-store.
// Strides: 104 shorts = 52 dw == 20 mod 32 -> 2-way max read aliasing (benign).
// R11 lesson: 4-tile waves (64 VGPR of weights) spill -> 2 tiles/wave max.
// R12 lesson: x-in-regs + setprio regressed; cvt_pk + merged-rcp gate = real.
// R13 (398us): VALU issue -110cy/step verified but wall only -24cy -> lockstep
//   (barrier -> ds_read latency -> MFMA chain -> trans gates -> write) is the
//   binding structure; all 4 waves/SIMD in same phase.
// R14 changes (attack issue stream + exposed latency within lockstep):
//  * PACKED-F32 gates: both tiles' gate chains as float2v lane0/lane1 ->
//    v_pk_{add,mul,fma}_f32 (full-rate on gfx90a+), ~28 VALU -> ~14 pk.
//  * MFMA chain split: two independent partial accs + vector add, removes
//    1-2 exposed MFMA-latency depths.
//  * Hot-loop barrier = s_waitcnt lgkmcnt(0) + s_barrier (drops the
//    vmcnt(0)/expcnt(0) drain __syncthreads would force; only this-wave x
//    loads are in flight -> waited at use, not at barrier).
#define A1STR 104
#define A2STR 104

typedef __attribute__((ext_vector_type(8))) short short8;
typedef __attribute__((ext_vector_type(4))) float floatx4;
typedef __attribute__((ext_vector_type(2))) float float2v;

#define LOG2E 1.4426950408889634f

__device__ __forceinline__ short f2bf_rne(float v) {
  unsigned u = __float_as_uint(v);
  return (short)((u + 0x7FFFu + ((u >> 16) & 1u)) >> 16);
}
__device__ __forceinline__ float rcp_(float x) { return __builtin_amdgcn_rcpf(x); }
__device__ __forceinline__ float exp2_(float x) { return __builtin_amdgcn_exp2f(x); }

// one-instruction RNE pack of two f32 -> 2x bf16 (no builtin on gfx950)
__device__ __forceinline__ unsigned cvt_pk_bf16(float lo, float hi) {
  unsigned r;
  asm("v_cvt_pk_bf16_f32 %0, %1, %2" : "=v"(r) : "v"(lo), "v"(hi));
  return r;
}

// Hot-loop barrier: LDS-publish only. Required semantics: this wave's
// ds_writes retired (lgkmcnt) before s_barrier; reads pinned after via
// volatile-asm fences (s_barrier intrinsic has side effects -> volatile asm
// is not reordered across it).
__device__ __forceinline__ void barrier_lds() {
  asm volatile("s_waitcnt lgkmcnt(0)" ::: "memory");
  __builtin_amdgcn_s_barrier();
  asm volatile("" ::: "memory");
}

// Packed gates for both tiles (lane0 = tile a, lane1 = tile b).
// gates pre-scaled: p[0,1,3] by LOG2E, p[2] by 2*LOG2E. rcp-fused, f-rcp and
// ig-rcp merged (R12-verified):
//   t1 = (1+A)(G+1); t2 = (1+F)
//   c  = (c*t1 + (G-1)*t2) * rcp(t1*t2)
//   h  = (C-1) * rcp((1+O)(C+1)),  C = exp2(2*log2e*c)
__device__ __forceinline__ float2v gate_h_pk(const floatx4 pa, const floatx4 pb,
                                             float2v& c) {
  float2v A = {exp2_(-pa[0]), exp2_(-pb[0])};
  float2v F = {exp2_(-pa[1]), exp2_(-pb[1])};
  float2v G = {exp2_( pa[2]), exp2_( pb[2])};
  float2v O = {exp2_(-pa[3]), exp2_(-pb[3])};
  const float2v one = {1.f, 1.f};
  float2v t1 = (one + A) * (G + one);
  float2v t2 = one + F;
  float2v num = c * t1 + (G - one) * t2;
  float2v d  = t1 * t2;
  float2v rd = {rcp_(d.x), rcp_(d.y)};
  c = num * rd;
  float2v c2 = c * (2.f * LOG2E);
  float2v C = {exp2_(c2.x), exp2_(c2.y)};
  float2v e = (one + O) * (C + one);
  float2v re = {rcp_(e.x), rcp_(e.y)};
  return (C - one) * re;
}

// unit stored at LDS h-position p
__device__ __forceinline__ int uofp(int p) {
  return (p & ~7) + ((p & 7) >> 1) + ((p & 1) << 2);
}

// Layer-1 weight at A-frag k-slot (K1=96): k<64 pairs h1 positions, 64..70 x
__device__ __forceinline__ short w1elem(int k, int n, float wsc,
                                        const float* __restrict__ Wih0,
                                        const float* __restrict__ Whh0) {
  float v;
  if      (k < 64) { v = Whh0[n*64 + uofp(k)]; }
  else if (k < 71) { v = Wih0[n*7 + (k - 64)]; }
  else return (short)0;
  return f2bf_rne(v * wsc);
}
// Layer-2 weight (K2=128): k<64 pairs h1 positions, 64..127 pairs h2 positions
__device__ __forceinline__ short w2elem(int k, int n, float wsc,
                                        const float* __restrict__ Wih1,
                                        const float* __restrict__ Whh1) {
  float v;
  if (k < 64) { v = Wih1[n*64 + uofp(k)]; }
  else        { v = Whh1[n*64 + uofp(k - 64)]; }
  return f2bf_rne(v * wsc);
}

// A = weights (first arg), B = h (second arg)
#define MFMA(A, B, C) __builtin_amdgcn_mfma_f32_16x16x32_bf16((A), (B), (C), 0, 0, 0)

__global__ __launch_bounds__(NTHREADS, 4) void lstm_fused(
    const float* __restrict__ x,
    const float* __restrict__ Wih0, const float* __restrict__ Whh0,
    const float* __restrict__ bih0, const float* __restrict__ bhh0,
    const float* __restrict__ Wih1, const float* __restrict__ Whh1,
    const float* __restrict__ bih1, const float* __restrict__ bhh1,
    const float* __restrict__ Wfc,  const float* __restrict__ bfc,
    float* __restrict__ out)
{
  __shared__ __align__(16) short A1[2][MB][A1STR];
  __shared__ __align__(16) short A2[2][MB][A2STR];
  __shared__ float h2f[MB][HID + 4];

  const int tid  = threadIdx.x;
  const int lane = tid & 63;
  const int wave = tid >> 6;           // 0..15
  const int wl   = wave & 7;           // index within layer group
  const bool isL1 = wave < 8;
  const int l15  = lane & 15;          // batch column
  const int quad = lane >> 4;
  const int quad8= quad * 8;
  const int g4   = l15 & 3;
  const int b0   = blockIdx.x * MB;
  const int u0   = wl*8 + quad;        // tile-0 owned unit
  const int u1   = u0 + 4;             // tile-1 owned unit
  const int hpos = wl*8 + 2*quad;      // packed h position (shorts, even)
  const int n0   = g4*64 + (wl*8 + (l15 >> 2));   // tile-0 weight row
  const int n1   = n0 + 4;                        // tile-1 weight row
  const float wsc = (g4 == 2) ? 2.f * LOG2E : LOG2E;
  const floatx4 zero4 = {0.f, 0.f, 0.f, 0.f};

  // ---- zero both staging buffers (h(-1) = 0, x pad = 0) ----
  for (int i = tid; i < 2*MB*A1STR/2; i += NTHREADS) ((unsigned*)A1)[i] = 0u;
  for (int i = tid; i < 2*MB*A2STR/2; i += NTHREADS) ((unsigned*)A2)[i] = 0u;
  __syncthreads();   // zeroing fully done before anyone stages x into A1[0]

  // ---- biases for owned units (this thread's layer) ----
  const float* bi_ = isL1 ? bih0 : bih1;
  const float* bh_ = isL1 ? bhh0 : bhh1;
  floatx4 bia, bib;
  #pragma unroll
  for (int g = 0; g < 4; ++g) {
    float ws = (g == 2) ? 2.f * LOG2E : LOG2E;
    bia[g] = (bi_[g*64 + u0] + bh_[g*64 + u0]) * ws;
    bib[g] = (bi_[g*64 + u1] + bh_[g*64 + u1]) * ws;
  }

  // ---- x staging: spread across all 8 L1 waves (2 batch rows each).
  // Pair-packed: lane xd2 in 0..3 owns x elements {2*xd2, 2*xd2+1} of its
  // row (element 7 is the zero pad; x[7] never touched -> no OOB). One
  // cvt_pk + one b32 LDS write per lane; prefetch distance = one full step.
  const int xd2  = lane & 31;          // 0..3 active
  const int xrow = 2*wl + (lane >> 5);
  const bool xact = isL1 && (xd2 < 4);
  const float* xbase = x + ((size_t)(b0 + xrow) * T_SEQ) * 7 + 2*xd2;
  float xc0 = 0.f, xc1 = 0.f;
  if (xact) {
    *(unsigned*)&A1[0][xrow][64 + 2*xd2] =
        cvt_pk_bf16(xbase[0], (xd2 < 3) ? xbase[1] : 0.f);
    xc0 = xbase[7];
    xc1 = (xd2 < 3) ? xbase[8] : 0.f;
  }

  // ---- weight A-fragments (per layer group; tiles a/b) ----
  short8 WA[4], WB[4];
  if (isL1) {
    #pragma unroll
    for (int ks = 0; ks < 3; ++ks) {
      short8 fa, fb;
      #pragma unroll
      for (int jj = 0; jj < 8; ++jj) {
        fa[jj] = w1elem(ks*32 + quad8 + jj, n0, wsc, Wih0, Whh0);
        fb[jj] = w1elem(ks*32 + quad8 + jj, n1, wsc, Wih0, Whh0);
      }
      WA[ks] = fa; WB[ks] = fb;
    }
  } else {
    #pragma unroll
    for (int ks = 0; ks < 4; ++ks) {
      short8 fa, fb;
      #pragma unroll
      for (int jj = 0; jj < 8; ++jj) {
        fa[jj] = w2elem(ks*32 + quad8 + jj, n0, wsc, Wih1, Whh1);
        fb[jj] = w2elem(ks*32 + quad8 + jj, n1, wsc, Wih1, Whh1);
      }
      WA[ks] = fa; WB[ks] = fb;
    }
  }
  __syncthreads();

  float2v cc = {0.f, 0.f};   // c-state for owned (layer, unit) pair {a,b}

#define STEP_X(NXT, XT)                                                      \
    if (xact) {                                                              \
      *(unsigned*)&A1[NXT][xrow][64 + 2*xd2] = cvt_pk_bf16(xc0, xc1);        \
      xc0 = xbase[7 * (XT)];                                                 \
      xc1 = (xd2 < 3) ? xbase[7 * (XT) + 1] : 0.f;                           \
    }

#define STEP_FULL(CUR, NXT, IT)                                              \
  {                                                                          \
    if (isL1) {                                                              \
      int xt_ = (IT) + 2; if (xt_ > T_SEQ - 1) xt_ = T_SEQ - 1;              \
      STEP_X(NXT, xt_)                                                       \
      short8 hf0 = *(const short8*)&A1[CUR][l15][     quad8];                \
      short8 hf1 = *(const short8*)&A1[CUR][l15][32 + quad8];                \
      short8 hfx = *(const short8*)&A1[CUR][l15][64 + quad8];                \
      floatx4 qa = MFMA(WA[0], hf0, bia);                                    \
      floatx4 qb = MFMA(WB[0], hf0, bib);                                    \
      floatx4 ra = MFMA(WA[2], hfx, zero4);                                  \
      floatx4 rb = MFMA(WB[2], hfx, zero4);                                  \
      qa = MFMA(WA[1], hf1, qa);                                             \
      qb = MFMA(WB[1], hf1, qb);                                             \
      float2v h = gate_h_pk(qa + ra, qb + rb, cc);                           \
      *(unsigned*)&A1[NXT][l15][hpos] = cvt_pk_bf16(h.x, h.y);               \
    } else {                                                                 \
      short8 hf0 = *(const short8*)&A1[CUR][l15][     quad8];                \
      short8 hf1 = *(const short8*)&A1[CUR][l15][32 + quad8];                \
      short8 h20 = *(const short8*)&A2[CUR][l15][     quad8];                \
      short8 h21 = *(const short8*)&A2[CUR][l15][32 + quad8];                \
      floatx4 qa = MFMA(WA[0], hf0, bia);                                    \
      floatx4 qb = MFMA(WB[0], hf0, bib);                                    \
      floatx4 ra = MFMA(WA[2], h20, zero4);                                  \
      floatx4 rb = MFMA(WB[2], h20, zero4);                                  \
      qa = MFMA(WA[1], hf1, qa);                                             \
      qb = MFMA(WB[1], hf1, qb);                                             \
      ra = MFMA(WA[3], h21, ra);                                             \
      rb = MFMA(WB[3], h21, rb);                                             \
      float2v h = gate_h_pk(qa + ra, qb + rb, cc);                           \
      *(unsigned*)&A2[NXT][l15][hpos] = cvt_pk_bf16(h.x, h.y);               \
    }                                                                        \
    barrier_lds();                                                           \
  }

  // ---- it = 0: L1 only (A2[1] keeps zeros = h2(-1)) ----
  {
    if (isL1) {
      STEP_X(1, 2)
      short8 hf0 = *(const short8*)&A1[0][l15][     quad8];
      short8 hf1 = *(const short8*)&A1[0][l15][32 + quad8];
      short8 hfx = *(const short8*)&A1[0][l15][64 + quad8];
      floatx4 qa = MFMA(WA[0], hf0, bia);
      floatx4 qb = MFMA(WB[0], hf0, bib);
      floatx4 ra = MFMA(WA[2], hfx, zero4);
      floatx4 rb = MFMA(WB[2], hfx, zero4);
      qa = MFMA(WA[1], hf1, qa);
      qb = MFMA(WB[1], hf1, qb);
      float2v h = gate_h_pk(qa + ra, qb + rb, cc);
      *(unsigned*)&A1[1][l15][hpos] = cvt_pk_bf16(h.x, h.y);
    }
    barrier_lds();
  }

  // ---- main: it = 1..510, two steps per trip ----
  #pragma unroll 1
  for (int k = 0; k < 255; ++k) {
    STEP_FULL(1, 0, 2*k + 1)
    STEP_FULL(0, 1, 2*k + 2)
  }
  // ---- it = 511 ----
  STEP_FULL(1, 0, 511)

  // ---- it = 512: L2 only; write final h2 as f32 (natural unit index) ----
  {
    if (!isL1) {
      short8 hf0 = *(const short8*)&A1[0][l15][     quad8];
      short8 hf1 = *(const short8*)&A1[0][l15][32 + quad8];
      short8 h20 = *(const short8*)&A2[0][l15][     quad8];
      short8 h21 = *(const short8*)&A2[0][l15][32 + quad8];
      floatx4 qa = MFMA(WA[0], hf0, bia);
      floatx4 qb = MFMA(WB[0], hf0, bib);
      floatx4 ra = MFMA(WA[2], h20, zero4);
      floatx4 rb = MFMA(WB[2], h20, zero4);
      qa = MFMA(WA[1], hf1, qa);
      qb = MFMA(WB[1], hf1, qb);
      ra = MFMA(WA[3], h21, ra);
      rb = MFMA(WB[3], h21, rb);
      float2v h = gate_h_pk(qa + ra, qb + rb, cc);
      h2f[l15][u0] = h.x;
      h2f[l15][u1] = h.y;
    }
    __syncthreads();
  }

  // ---- final FC ----
  if (tid < MB * 4) {
    int bbf = tid >> 2, o = tid & 3;
    float acc = bfc[o];
    #pragma unroll 8
    for (int kk = 0; kk < HID; ++kk) acc += h2f[bbf][kk] * Wfc[o*HID + kk];
    out[(size_t)(b0 + bbf) * 4 + o] = acc;
  }
}

extern "C" void kernel_launch(void* const* d_in, const int* in_sizes, int n_in,
                              void* d_out, int out_size, void* d_ws, size_t ws_size,
                              hipStream_t stream) {
  const float* x    = (const float*)d_in[0];
  const float* Wih0 = (const float*)d_in[1];
  const float* Whh0 = (const float*)d_in[2];
  const float* bih0 = (const float*)d_in[3];
  const float* bhh0 = (const float*)d_in[4];
  const float* Wih1 = (const float*)d_in[5];
  const float* Whh1 = (const float*)d_in[6];
  const float* bih1 = (const float*)d_in[7];
  const float* bhh1 = (const float*)d_in[8];
  const float* Wfc  = (const float*)d_in[9];
  const float* bfc  = (const float*)d_in[10];
  (void)d_ws; (void)ws_size; (void)n_in; (void)out_size;

  const int B = in_sizes[0] / (T_SEQ * 7);   // 4096
  dim3 grid(B / MB);
  lstm_fused<<<grid, NTHREADS, 0, stream>>>(x, Wih0, Whh0, bih0, bhh0,
                                            Wih1, Whh1, bih1, bhh1, Wfc, bfc,
                                            (float*)d_out);
}

// Round 5
// 426.301 us; speedup vs baseline: 1.0524x; 1.0524x over previous
//
#include <hip/hip_runtime.h>

#define T_SEQ 512
#define HID 64
#define MB 16             // batch rows per block
#define NTHREADS 512      // 8 waves: 0-3 layer1 (4 tiles each), 4-7 layer2 (4 tiles)
// OPERAND-FLIPPED MFMA: A = weights (regs), B = h (LDS). D[gate-unit][batch].
// R15 RESTRUCTURE (8 waves x 4 tiles, was 16 x 2):
//   All waves of a layer read IDENTICAL B-fragments (h is shared input; only
//   weights differ per wave). The CU-wide LDS pipe served 56 redundant
//   ds_read_b128/step (~672 cy, ~36% of the 1862-cy step). Halving wave count
//   while doubling tiles/wave keeps MFMA/gate totals constant but cuts reads
//   to 28/step. VGPR: 4 tiles of weights = 64 VGPR; fits under the
//   launch_bounds(512,2) cap of 256 (R11's spill was at the ,4 cap of 128).
//   Each thread now has 4 independent gate chains (ILP=4).
// R14 lesson: packed-f32 gates cut issue (-110cy verified) but serialized the
//   two gate chains into one long-latency chain (+200cy wall) -> REVERTED to
//   scalar gates (gate phase is latency-bound, not issue-bound).
// R13 lesson: VALU cuts real but lockstep structure limits their wall impact.
// R12 lesson: x-in-regs + setprio regressed; cvt_pk + merged-rcp gate = real.
// UNIT PERMUTATION: LDS position p holds unit U(p) = (p&~7)+((p&7)>>1)+((p&1)<<2)
// -> thread (w0,quad) owns units {ub,ub+4} at positions {2q,2q+1} of 8-block
//    w0*2 and {ub+8,ub+12} at the same slots of 8-block w0*2+1: two b32 stores.
// Strides: 104 shorts = 52 dw == 20 mod 32 -> 2-way max read aliasing (benign).
#define A1STR 104
#define A2STR 104

typedef __attribute__((ext_vector_type(8))) short short8;
typedef __attribute__((ext_vector_type(4))) float floatx4;

#define LOG2E 1.4426950408889634f

__device__ __forceinline__ short f2bf_rne(float v) {
  unsigned u = __float_as_uint(v);
  return (short)((u + 0x7FFFu + ((u >> 16) & 1u)) >> 16);
}
__device__ __forceinline__ float rcp_(float x) { return __builtin_amdgcn_rcpf(x); }
__device__ __forceinline__ float exp2_(float x) { return __builtin_amdgcn_exp2f(x); }

// one-instruction RNE pack of two f32 -> 2x bf16 (no builtin on gfx950)
__device__ __forceinline__ unsigned cvt_pk_bf16(float lo, float hi) {
  unsigned r;
  asm("v_cvt_pk_bf16_f32 %0, %1, %2" : "=v"(r) : "v"(lo), "v"(hi));
  return r;
}

// Hot-loop barrier: LDS-publish only (drops the vmcnt(0)/expcnt(0) drain that
// __syncthreads forces; only this-wave x loads are in flight, waited at use).
__device__ __forceinline__ void barrier_lds() {
  asm volatile("s_waitcnt lgkmcnt(0)" ::: "memory");
  __builtin_amdgcn_s_barrier();
  asm volatile("" ::: "memory");
}

// Scalar gates (R3-verified; R14 showed packing the chains hurts latency).
// gates pre-scaled: p[0,1,3] by LOG2E, p[2] by 2*LOG2E. rcp-fused, f-rcp and
// ig-rcp merged (7 trans):
//   t1 = (1+A)(G+1); t2 = (1+F)
//   c  = (c*t1 + (G-1)*t2) * rcp(t1*t2)
//   h  = (C-1) * rcp((1+O)(C+1)),  C = exp2(2*log2e*c)
__device__ __forceinline__ float gate_h(const floatx4 p, float& c) {
  float A = exp2_(-p[0]);
  float F = exp2_(-p[1]);
  float G = exp2_(p[2]);
  float O = exp2_(-p[3]);
  float t1 = (1.f + A) * (G + 1.f);
  float t2 = 1.f + F;
  float num = c * t1 + (G - 1.f) * t2;
  c = num * rcp_(t1 * t2);
  float C = exp2_((2.f * LOG2E) * c);
  return (C - 1.f) * rcp_((1.f + O) * (C + 1.f));
}

// unit stored at LDS h-position p
__device__ __forceinline__ int uofp(int p) {
  return (p & ~7) + ((p & 7) >> 1) + ((p & 1) << 2);
}

// Layer-1 weight at A-frag k-slot (K1=96): k<64 pairs h1 positions, 64..70 x
__device__ __forceinline__ short w1elem(int k, int n, float wsc,
                                        const float* __restrict__ Wih0,
                                        const float* __restrict__ Whh0) {
  float v;
  if      (k < 64) { v = Whh0[n*64 + uofp(k)]; }
  else if (k < 71) { v = Wih0[n*7 + (k - 64)]; }
  else return (short)0;
  return f2bf_rne(v * wsc);
}
// Layer-2 weight (K2=128): k<64 pairs h1 positions, 64..127 pairs h2 positions
__device__ __forceinline__ short w2elem(int k, int n, float wsc,
                                        const float* __restrict__ Wih1,
                                        const float* __restrict__ Whh1) {
  float v;
  if (k < 64) { v = Wih1[n*64 + uofp(k)]; }
  else        { v = Whh1[n*64 + uofp(k - 64)]; }
  return f2bf_rne(v * wsc);
}

// A = weights (first arg), B = h (second arg)
#define MFMA(A, B, C) __builtin_amdgcn_mfma_f32_16x16x32_bf16((A), (B), (C), 0, 0, 0)

__global__ __launch_bounds__(NTHREADS, 2) void lstm_fused(
    const float* __restrict__ x,
    const float* __restrict__ Wih0, const float* __restrict__ Whh0,
    const float* __restrict__ bih0, const float* __restrict__ bhh0,
    const float* __restrict__ Wih1, const float* __restrict__ Whh1,
    const float* __restrict__ bih1, const float* __restrict__ bhh1,
    const float* __restrict__ Wfc,  const float* __restrict__ bfc,
    float* __restrict__ out)
{
  __shared__ __align__(16) short A1[2][MB][A1STR];
  __shared__ __align__(16) short A2[2][MB][A2STR];
  __shared__ float h2f[MB][HID + 4];

  const int tid  = threadIdx.x;
  const int lane = tid & 63;
  const int wave = tid >> 6;           // 0..7
  const int w0   = wave & 3;           // index within layer group
  const bool isL1 = wave < 4;
  const int l15  = lane & 15;          // batch column (output) / A-frag row
  const int quad = lane >> 4;
  const int quad8= quad * 8;
  const int g4   = l15 & 3;
  const int b0   = blockIdx.x * MB;
  const int ub   = w0*16 + quad;       // owned units: ub, ub+4, ub+8, ub+12
  const int hp0  = w0*16 + 2*quad;     // packs (h_t0, h_t1)   [shorts, even]
  const int hp1  = hp0 + 8;            // packs (h_t2, h_t3)
  const float wsc = (g4 == 2) ? 2.f * LOG2E : LOG2E;

  // ---- zero both staging buffers (h(-1) = 0, x pad = 0) ----
  for (int i = tid; i < 2*MB*A1STR/2; i += NTHREADS) ((unsigned*)A1)[i] = 0u;
  for (int i = tid; i < 2*MB*A2STR/2; i += NTHREADS) ((unsigned*)A2)[i] = 0u;
  __syncthreads();   // zeroing fully done before anyone stages x into A1[0]

  // ---- biases for owned units (this thread's layer) ----
  const float* bi_ = isL1 ? bih0 : bih1;
  const float* bh_ = isL1 ? bhh0 : bhh1;
  floatx4 bs0, bs1, bs2, bs3;
  #pragma unroll
  for (int g = 0; g < 4; ++g) {
    float ws = (g == 2) ? 2.f * LOG2E : LOG2E;
    bs0[g] = (bi_[g*64 + ub     ] + bh_[g*64 + ub     ]) * ws;
    bs1[g] = (bi_[g*64 + ub + 4 ] + bh_[g*64 + ub + 4 ]) * ws;
    bs2[g] = (bi_[g*64 + ub + 8 ] + bh_[g*64 + ub + 8 ]) * ws;
    bs3[g] = (bi_[g*64 + ub + 12] + bh_[g*64 + ub + 12]) * ws;
  }

  // ---- x staging: 4 L1 waves x 4 rows each (row = 4*w0 + quad).
  // Pair-packed: lane xd2 in 0..3 owns x elements {2*xd2, 2*xd2+1} of its
  // row (element 7 is the zero pad; x[7] never touched -> no OOB). One
  // cvt_pk + one b32 LDS write per lane; prefetch distance = one full step.
  const int xd2  = l15;                // 0..3 active
  const int xrow = 4*w0 + quad;
  const bool xact = isL1 && (xd2 < 4);
  const float* xbase = x + ((size_t)(b0 + xrow) * T_SEQ) * 7 + 2*xd2;
  float xc0 = 0.f, xc1 = 0.f;
  if (xact) {
    *(unsigned*)&A1[0][xrow][64 + 2*xd2] =
        cvt_pk_bf16(xbase[0], (xd2 < 3) ? xbase[1] : 0.f);
    xc0 = xbase[7];
    xc1 = (xd2 < 3) ? xbase[8] : 0.f;
  }

  // ---- weight A-fragments: 4 tiles per wave ----
  short8 W0[4], W1[4], W2[4], W3[4];
#define LOADW1(Wt, t)                                                        \
  { int nt = g4*64 + w0*16 + 4*(t) + (l15 >> 2);                             \
    _Pragma("unroll")                                                        \
    for (int ks = 0; ks < 3; ++ks) { short8 f;                               \
      _Pragma("unroll")                                                      \
      for (int jj = 0; jj < 8; ++jj)                                         \
        f[jj] = w1elem(ks*32 + quad8 + jj, nt, wsc, Wih0, Whh0);             \
      Wt[ks] = f; } }
#define LOADW2(Wt, t)                                                        \
  { int nt = g4*64 + w0*16 + 4*(t) + (l15 >> 2);                             \
    _Pragma("unroll")                                                        \
    for (int ks = 0; ks < 4; ++ks) { short8 f;                               \
      _Pragma("unroll")                                                      \
      for (int jj = 0; jj < 8; ++jj)                                         \
        f[jj] = w2elem(ks*32 + quad8 + jj, nt, wsc, Wih1, Whh1);             \
      Wt[ks] = f; } }
  if (isL1) {
    LOADW1(W0, 0) LOADW1(W1, 1) LOADW1(W2, 2) LOADW1(W3, 3)
  } else {
    LOADW2(W0, 0) LOADW2(W1, 1) LOADW2(W2, 2) LOADW2(W3, 3)
  }
  __syncthreads();

  float c0 = 0.f, c1 = 0.f, c2 = 0.f, c3 = 0.f;   // c-state, 4 owned units

#define STEP_X(NXT, XT)                                                      \
    if (xact) {                                                              \
      *(unsigned*)&A1[NXT][xrow][64 + 2*xd2] = cvt_pk_bf16(xc0, xc1);        \
      xc0 = xbase[7 * (XT)];                                                 \
      xc1 = (xd2 < 3) ? xbase[7 * (XT) + 1] : 0.f;                           \
    }

// Round-robin MFMA issue across the 4 independent tile chains.
#define L1_MFMAS                                                             \
      floatx4 p0 = MFMA(W0[0], hf0, bs0);                                    \
      floatx4 p1 = MFMA(W1[0], hf0, bs1);                                    \
      floatx4 p2 = MFMA(W2[0], hf0, bs2);                                    \
      floatx4 p3 = MFMA(W3[0], hf0, bs3);                                    \
      p0 = MFMA(W0[1], hf1, p0);  p1 = MFMA(W1[1], hf1, p1);                 \
      p2 = MFMA(W2[1], hf1, p2);  p3 = MFMA(W3[1], hf1, p3);                 \
      p0 = MFMA(W0[2], hfx, p0);  p1 = MFMA(W1[2], hfx, p1);                 \
      p2 = MFMA(W2[2], hfx, p2);  p3 = MFMA(W3[2], hfx, p3);

#define L2_MFMAS                                                             \
      floatx4 p0 = MFMA(W0[0], hf0, bs0);                                    \
      floatx4 p1 = MFMA(W1[0], hf0, bs1);                                    \
      floatx4 p2 = MFMA(W2[0], hf0, bs2);                                    \
      floatx4 p3 = MFMA(W3[0], hf0, bs3);                                    \
      p0 = MFMA(W0[1], hf1, p0);  p1 = MFMA(W1[1], hf1, p1);                 \
      p2 = MFMA(W2[1], hf1, p2);  p3 = MFMA(W3[1], hf1, p3);                 \
      p0 = MFMA(W0[2], h20, p0);  p1 = MFMA(W1[2], h20, p1);                 \
      p2 = MFMA(W2[2], h20, p2);  p3 = MFMA(W3[2], h20, p3);                 \
      p0 = MFMA(W0[3], h21, p0);  p1 = MFMA(W1[3], h21, p1);                 \
      p2 = MFMA(W2[3], h21, p2);  p3 = MFMA(W3[3], h21, p3);

#define GATES_AND_WRITE(DST)                                                 \
      float h0 = gate_h(p0, c0);                                             \
      float h1 = gate_h(p1, c1);                                             \
      float h2 = gate_h(p2, c2);                                             \
      float h3 = gate_h(p3, c3);                                             \
      *(unsigned*)&DST[l15][hp0] = cvt_pk_bf16(h0, h1);                      \
      *(unsigned*)&DST[l15][hp1] = cvt_pk_bf16(h2, h3);

#define STEP_FULL(CUR, NXT, IT)                                              \
  {                                                                          \
    if (isL1) {                                                              \
      int xt_ = (IT) + 2; if (xt_ > T_SEQ - 1) xt_ = T_SEQ - 1;              \
      STEP_X(NXT, xt_)                                                       \
      short8 hf0 = *(const short8*)&A1[CUR][l15][     quad8];                \
      short8 hf1 = *(const short8*)&A1[CUR][l15][32 + quad8];                \
      short8 hfx = *(const short8*)&A1[CUR][l15][64 + quad8];                \
      L1_MFMAS                                                               \
      GATES_AND_WRITE(A1[NXT])                                               \
    } else {                                                                 \
      short8 hf0 = *(const short8*)&A1[CUR][l15][     quad8];                \
      short8 hf1 = *(const short8*)&A1[CUR][l15][32 + quad8];                \
      short8 h20 = *(const short8*)&A2[CUR][l15][     quad8];                \
      short8 h21 = *(const short8*)&A2[CUR][l15][32 + quad8];                \
      L2_MFMAS                                                               \
      GATES_AND_WRITE(A2[NXT])                                               \
    }                                                                        \
    barrier_lds();                                                           \
  }

  // ---- it = 0: L1 only (A2[1] keeps zeros = h2(-1)) ----
  {
    if (isL1) {
      STEP_X(1, 2)
      short8 hf0 = *(const short8*)&A1[0][l15][     quad8];
      short8 hf1 = *(const short8*)&A1[0][l15][32 + quad8];
      short8 hfx = *(const short8*)&A1[0][l15][64 + quad8];
      L1_MFMAS
      GATES_AND_WRITE(A1[1])
    }
    barrier_lds();
  }

  // ---- main: it = 1..510, two steps per trip ----
  #pragma unroll 1
  for (int k = 0; k < 255; ++k) {
    STEP_FULL(1, 0, 2*k + 1)
    STEP_FULL(0, 1, 2*k + 2)
  }
  // ---- it = 511 ----
  STEP_FULL(1, 0, 511)

  // ---- it = 512: L2 only; write final h2 as f32 (natural unit index) ----
  {
    if (!isL1) {
      short8 hf0 = *(const short8*)&A1[0][l15][     quad8];
      short8 hf1 = *(const short8*)&A1[0][l15][32 + quad8];
      short8 h20 = *(const short8*)&A2[0][l15][     quad8];
      short8 h21 = *(const short8*)&A2[0][l15][32 + quad8];
      L2_MFMAS
      h2f[l15][ub     ] = gate_h(p0, c0);
      h2f[l15][ub + 4 ] = gate_h(p1, c1);
      h2f[l15][ub + 8 ] = gate_h(p2, c2);
      h2f[l15][ub + 12] = gate_h(p3, c3);
    }
    __syncthreads();
  }

  // ---- final FC ----
  if (tid < MB * 4) {
    int bbf = tid >> 2, o = tid & 3;
    float acc = bfc[o];
    #pragma unroll 8
    for (int kk = 0; kk < HID; ++kk) acc += h2f[bbf][kk] * Wfc[o*HID + kk];
    out[(size_t)(b0 + bbf) * 4 + o] = acc;
  }
}

extern "C" void kernel_launch(void* const* d_in, const int* in_sizes, int n_in,
                              void* d_out, int out_size, void* d_ws, size_t ws_size,
                              hipStream_t stream) {
  const float* x    = (const float*)d_in[0];
  const float* Wih0 = (const float*)d_in[1];
  const float* Whh0 = (const float*)d_in[2];
  const float* bih0 = (const float*)d_in[3];
  const float* bhh0 = (const float*)d_in[4];
  const float* Wih1 = (const float*)d_in[5];
  const float* Whh1 = (const float*)d_in[6];
  const float* bih1 = (const float*)d_in[7];
  const float* bhh1 = (const float*)d_in[8];
  const float* Wfc  = (const float*)d_in[9];
  const float* bfc  = (const float*)d_in[10];
  (void)d_ws; (void)ws_size; (void)n_in; (void)out_size;

  const int B = in_sizes[0] / (T_SEQ * 7);   // 4096
  dim3 grid(B / MB);
  lstm_fused<<<grid, NTHREADS, 0, stream>>>(x, Wih0, Whh0, bih0, bhh0,
                                            Wih1, Whh1, bih1, bhh1, Wfc, bfc,
                                            (float*)d_out);
}